// Round 4
// baseline (345.962 us; speedup 1.0000x reference)
//
#include <hip/hip_runtime.h>
#include <hip/hip_bf16.h>

// KNN_itc: out[b][n] = sum over support descriptors m (441) of top-3 (over 441
// query descriptors) cosine similarities, C=640, bf16 MFMA.
//
// R4:
//  - norm_kernel : inv L2 norms (552 blocks, coalesced)
//  - xpose_kernel: 2800 blocks (img x 7 hw-tiles x 5 ch-slabs), one barrier,
//                  writes MFMA-fragment-major chunks: chunk[(img*28+rb)*20+kt][512],
//                  element (row=rb*16+r16, c=kt*32+k32) at chunk*512 + r16*32 + k32.
//  - gemm_top3   : no LDS/barriers in K-loop; explicit 2-deep parity double
//                  buffer (waits become vmcnt(11), one full iteration of
//                  latency tolerance); 28 MFMAs/wave/kt; in-register top-3 +
//                  shuffle merge + one atomicAdd per block.

#define B_IMGS 75
#define N_CLS  5
#define C_DIM  640
#define HW     441
#define HWP    448
#define NKT    20            // 640 / 32 k-chunks
#define NRB    28            // 448 / 16 row-blocks per image
#define CHUNK  512           // 16 rows x 32 k elems

typedef __attribute__((ext_vector_type(8))) short  short8;   // 8 x bf16
typedef __attribute__((ext_vector_type(4))) float  float4v;  // MFMA acc

__device__ __forceinline__ void ins3(float& t0, float& t1, float& t2, float v) {
    float m  = fminf(t0, v);
    t0 = fmaxf(t0, v);
    float m2 = fminf(t1, m);
    t1 = fmaxf(t1, m);
    t2 = fmaxf(t2, m2);
}

__device__ __forceinline__ short bf16bits(float x) {
    __hip_bfloat16 h = __float2bfloat16(x);
    return *(short*)&h;
}

// ---------------- kernel 1: inverse norms (4-way C split) ----------------
__global__ __launch_bounds__(256)
void norm_kernel(const float* __restrict__ q, const float* __restrict__ S,
                 float* __restrict__ invq, float* __restrict__ invs) {
    __shared__ float part[4][64];
    const int total = (B_IMGS + N_CLS) * HW;
    int l = threadIdx.x & 63, p = threadIdx.x >> 6;
    int pos = blockIdx.x * 64 + l;
    bool ok = pos < total;
    int posc = ok ? pos : (total - 1);
    int img = posc / HW;
    int hw  = posc - img * HW;
    const float* src = (img < B_IMGS) ? (q + (size_t)img * C_DIM * HW)
                                      : (S + (size_t)(img - B_IMGS) * C_DIM * HW);
    float ss = 0.f;
#pragma unroll 8
    for (int c = p * 160; c < (p + 1) * 160; ++c) {
        float v = src[(size_t)c * HW + hw];
        ss += v * v;
    }
    part[p][l] = ss;
    __syncthreads();
    if (threadIdx.x < 64) {
        float tot = part[0][l] + part[1][l] + part[2][l] + part[3][l];
        float inv = rsqrtf(tot);
        if (ok) {
            if (img < B_IMGS) invq[img * HW + hw] = inv;
            else              invs[(img - B_IMGS) * HW + hw] = inv;
        }
    }
}

// -------- kernel 2: transpose + normalize + bf16, fragment-tiled write --------
// block = (img, h0: 64-row hw tile, cs: 128-channel slab); 2800 blocks
__global__ __launch_bounds__(256)
void xpose_kernel(const float* __restrict__ q, const float* __restrict__ S,
                  const float* __restrict__ invq, const float* __restrict__ invs,
                  __hip_bfloat16* __restrict__ qn2, __hip_bfloat16* __restrict__ sn2) {
    __shared__ float tile[128][65];     // [c_local][hw_local]; 65: conflict-free
    int bid = blockIdx.x;
    int img = bid / 35;                 // 0..79 (0..74 = q, 75..79 = S)
    int rem = bid % 35;
    int h0  = rem / 5;                  // hw tile
    int cs  = rem % 5;                  // 128-ch slab
    const float* src; const float* inv; __hip_bfloat16* dst;
    if (img < B_IMGS) {
        src = q + (size_t)img * C_DIM * HW;
        inv = invq + img * HW;
        dst = qn2 + (size_t)img * NRB * NKT * CHUNK;
    } else {
        src = S + (size_t)(img - B_IMGS) * C_DIM * HW;
        inv = invs + (img - B_IMGS) * HW;
        dst = sn2 + (size_t)(img - B_IMGS) * NRB * NKT * CHUNK;
    }
    int t  = threadIdx.x;
    int hl = t & 63;
    int p  = t >> 6;
    int hw = h0 * 64 + hl;
    bool ok = hw < HW;
    int hwc = ok ? hw : (HW - 1);
    float iv = ok ? inv[hw] : 0.f;      // pad rows -> zeros (masked later anyway)

#pragma unroll
    for (int i = 0; i < 32; ++i) {
        int cl = p * 32 + i;
        tile[cl][hl] = src[(size_t)(cs * 128 + cl) * HW + hwc] * iv;  // coalesced
    }
    __syncthreads();

    int rl = t >> 2;                    // local hw row 0..63
    int k8 = (t & 3) * 8;
    int rb = h0 * 4 + (rl >> 4);
#pragma unroll
    for (int s = 0; s < 4; ++s) {       // 4 k-chunks in this slab
        short8 v;
#pragma unroll
        for (int j = 0; j < 8; ++j)
            v[j] = bf16bits(tile[s * 32 + k8 + j][rl]);   // <=2-way banks: free
        size_t off = ((size_t)rb * NKT + cs * 4 + s) * CHUNK + (rl & 15) * 32 + k8;
        *(short8*)(dst + off) = v;      // 1KiB coalesced wave store
    }
}

// ------------- gemm + fused top-3: 2-deep pipeline, no LDS in K-loop -------------
__global__ __launch_bounds__(256, 2)
void gemm_top3_kernel(const __hip_bfloat16* __restrict__ qn2,
                      const __hip_bfloat16* __restrict__ sn2,
                      float* __restrict__ out) {
    __shared__ float mrg[4][64][3];

    // XCD-grouping swizzle: all 35 (n,mt) blocks of image b on one XCD
    int id  = blockIdx.x;
    int xcd = id & 7;
    int j8  = id >> 3;
    int b   = (j8 / 35) * 8 + xcd;
    if (b >= B_IMGS) return;
    int inner = j8 % 35;
    int n  = inner / 7;
    int mt = inner % 7;

    int tid  = threadIdx.x;
    int w    = tid >> 6;
    int lane = tid & 63;
    int c16  = lane & 15;
    int quad = lane >> 4;
    int frag = c16 * 32 + quad * 8;     // within-chunk fragment offset

    const __hip_bfloat16* aptr[7];
#pragma unroll
    for (int r = 0; r < 7; ++r)
        aptr[r] = qn2 + ((size_t)b * NRB + r * 4 + w) * NKT * CHUNK + frag;
    const __hip_bfloat16* bptr[4];
#pragma unroll
    for (int j = 0; j < 4; ++j)
        bptr[j] = sn2 + ((size_t)n * NRB + mt * 4 + j) * NKT * CHUNK + frag;

    float4v acc[7][4];
#pragma unroll
    for (int r = 0; r < 7; ++r)
#pragma unroll
        for (int j = 0; j < 4; ++j)
            acc[r][j] = (float4v){0.f, 0.f, 0.f, 0.f};

    // 2-deep parity double buffer
    short8 Ab[2][7], Bb[2][4];
#pragma unroll
    for (int r = 0; r < 7; ++r) {
        Ab[0][r] = *(const short8*)(aptr[r]);
        Ab[1][r] = *(const short8*)(aptr[r] + CHUNK);
    }
#pragma unroll
    for (int j = 0; j < 4; ++j) {
        Bb[0][j] = *(const short8*)(bptr[j]);
        Bb[1][j] = *(const short8*)(bptr[j] + CHUNK);
    }

#pragma unroll
    for (int kt = 0; kt < NKT; ++kt) {
        const int cur = kt & 1;
#pragma unroll
        for (int r = 0; r < 7; ++r)
#pragma unroll
            for (int j = 0; j < 4; ++j)
                acc[r][j] = __builtin_amdgcn_mfma_f32_16x16x32_bf16(
                    Ab[cur][r], Bb[cur][j], acc[r][j], 0, 0, 0);
        if (kt + 2 < NKT) {
#pragma unroll
            for (int r = 0; r < 7; ++r)
                Ab[cur][r] = *(const short8*)(aptr[r] + (kt + 2) * CHUNK);
#pragma unroll
            for (int j = 0; j < 4; ++j)
                Bb[cur][j] = *(const short8*)(bptr[j] + (kt + 2) * CHUNK);
        }
    }

    // ---- in-register top-3 over this wave's 112 rows, per owned column ----
    float T0[4], T1[4], T2[4];
#pragma unroll
    for (int j = 0; j < 4; ++j) { T0[j] = -1e30f; T1[j] = -1e30f; T2[j] = -1e30f; }
#pragma unroll
    for (int r = 0; r < 7; ++r)
#pragma unroll
        for (int j = 0; j < 4; ++j)
#pragma unroll
            for (int g = 0; g < 4; ++g) {
                int row = r * 64 + w * 16 + quad * 4 + g;   // C layout: row=quad*4+reg
                float v = (row < HW) ? acc[r][j][g] : -1e30f;
                ins3(T0[j], T1[j], T2[j], v);
            }

    // quad-butterfly merge (rows spread over lane bits 4,5)
#pragma unroll
    for (int j = 0; j < 4; ++j) {
#pragma unroll
        for (int d = 16; d <= 32; d <<= 1) {
            float o0 = __shfl_xor(T0[j], d, 64);
            float o1 = __shfl_xor(T1[j], d, 64);
            float o2 = __shfl_xor(T2[j], d, 64);
            ins3(T0[j], T1[j], T2[j], o0);
            ins3(T0[j], T1[j], T2[j], o1);
            ins3(T0[j], T1[j], T2[j], o2);
        }
    }

    // cross-wave merge via LDS
    if (quad == 0) {
#pragma unroll
        for (int j = 0; j < 4; ++j) {
            mrg[w][j * 16 + c16][0] = T0[j];
            mrg[w][j * 16 + c16][1] = T1[j];
            mrg[w][j * 16 + c16][2] = T2[j];
        }
    }
    __syncthreads();
    if (tid < 64) {
        int col = tid;
        float t0 = mrg[0][col][0], t1 = mrg[0][col][1], t2 = mrg[0][col][2];
#pragma unroll
        for (int ww = 1; ww < 4; ++ww) {
            ins3(t0, t1, t2, mrg[ww][col][0]);
            ins3(t0, t1, t2, mrg[ww][col][1]);
            ins3(t0, t1, t2, mrg[ww][col][2]);
        }
        float s = (mt * 64 + col < HW) ? (t0 + t1 + t2) : 0.f;
#pragma unroll
        for (int d = 32; d >= 1; d >>= 1) s += __shfl_xor(s, d, 64);
        if (tid == 0) atomicAdd(&out[b * N_CLS + n], s);
    }
}

extern "C" void kernel_launch(void* const* d_in, const int* in_sizes, int n_in,
                              void* d_out, int out_size, void* d_ws, size_t ws_size,
                              hipStream_t stream) {
    const float* q = (const float*)d_in[0];
    const float* S = (const float*)d_in[1];
    float* out = (float*)d_out;

    char* ws = (char*)d_ws;
    size_t off = 0;
    __hip_bfloat16* qn2 = (__hip_bfloat16*)(ws + off);
    off += (size_t)B_IMGS * NRB * NKT * CHUNK * 2;  off = (off + 255) & ~(size_t)255;
    __hip_bfloat16* sn2 = (__hip_bfloat16*)(ws + off);
    off += (size_t)N_CLS * NRB * NKT * CHUNK * 2;   off = (off + 255) & ~(size_t)255;
    float* invq = (float*)(ws + off);
    off += (size_t)B_IMGS * HW * 4;                 off = (off + 255) & ~(size_t)255;
    float* invs = (float*)(ws + off);

    hipMemsetAsync(d_out, 0, (size_t)out_size * sizeof(float), stream);

    int totald = (B_IMGS + N_CLS) * HW;
    norm_kernel<<<dim3((totald + 63) / 64), dim3(256), 0, stream>>>(q, S, invq, invs);
    xpose_kernel<<<dim3(80 * 35), dim3(256), 0, stream>>>(q, S, invq, invs, qn2, sn2);
    // 8 XCD groups x 350 slots; dead blocks (b>=75) exit immediately
    gemm_top3_kernel<<<dim3(8 * 350), dim3(256), 0, stream>>>(qn2, sn2, out);
}

// Round 5
// 291.262 us; speedup vs baseline: 1.1878x; 1.1878x over previous
//
#include <hip/hip_runtime.h>
#include <hip/hip_bf16.h>

// KNN_itc: out[b][n] = sum over support descriptors m (441) of top-3 (over 441
// query descriptors) cosine similarities, C=640, bf16 MFMA.
//
// R5:
//  - prep_kernel : ONE kernel, block=(img, 64-row hw tile). Pass1: sumsq over C
//    (coalesced). Pass2: L2-hot re-read, scale, single-rounded bf16 stash in
//    LDS [c][hw]. Pass3: pack short8 + fragment-major chunk writes:
//    chunk[(img*28+rb)*20+kt][512], elem(row=rb*16+r16, k=kt*32+k32) at
//    chunk*512 + r16*32 + k32.
//  - gemm_top3   : m97 structure. BK=64 slab = 64 chunks (56 A + 8 B) staged
//    via global_load_lds width=16 (chunk = 1KiB contiguous = wave-uniform base
//    + lane*16 — conforms to glds dest rule). 2 barriers/slab, 10 slabs.
//    Per wave/slab: 16 glds + 22 ds_read_b128 + 56 MFMA. LDS 67KB -> 2
//    blocks/CU. In-register top-3 + shuffle merge + one atomicAdd per block.

#define B_IMGS 75
#define N_CLS  5
#define C_DIM  640
#define HW     441
#define HWP    448
#define NKT    20            // 640 / 32 k-chunks
#define NRB    28            // 448 / 16 row-blocks per image
#define CHUNK  512           // 16 rows x 32 k elems = 1 KiB

typedef __attribute__((ext_vector_type(8))) short  short8;   // 8 x bf16
typedef __attribute__((ext_vector_type(4))) float  float4v;  // MFMA acc

__device__ __forceinline__ void ins3(float& t0, float& t1, float& t2, float v) {
    float m  = fminf(t0, v);
    t0 = fmaxf(t0, v);
    float m2 = fminf(t1, m);
    t1 = fmaxf(t1, m);
    t2 = fmaxf(t2, m2);
}

__device__ __forceinline__ void glds16(const __hip_bfloat16* g, __hip_bfloat16* l) {
    __builtin_amdgcn_global_load_lds(
        (const __attribute__((address_space(1))) unsigned int*)g,
        (__attribute__((address_space(3))) unsigned int*)l, 16, 0, 0);
}

// ---- fused prepass: norm + normalize + bf16 + fragment-tiled write ----
// block = (img 0..79, h0 0..6); 560 blocks x 256 threads
__global__ __launch_bounds__(256)
void prep_kernel(const float* __restrict__ q, const float* __restrict__ S,
                 __hip_bfloat16* __restrict__ qn2, __hip_bfloat16* __restrict__ sn2) {
    __shared__ __hip_bfloat16 tile[C_DIM][65];   // 83,200 B; [c][hw], pad->2-way free
    __shared__ float part[4][64];
    __shared__ float inv[64];

    int bid = blockIdx.x;
    int img = bid / 7;               // 0..79 (0..74 = q, 75..79 = S)
    int h0  = bid % 7;
    const float* src; __hip_bfloat16* dst;
    if (img < B_IMGS) {
        src = q + (size_t)img * C_DIM * HW;
        dst = qn2 + (size_t)img * NRB * NKT * CHUNK;
    } else {
        src = S + (size_t)(img - B_IMGS) * C_DIM * HW;
        dst = sn2 + (size_t)(img - B_IMGS) * NRB * NKT * CHUNK;
    }
    int t  = threadIdx.x;
    int hl = t & 63;                 // hw lane
    int p  = t >> 6;                 // 160-channel slice
    int hw = h0 * 64 + hl;
    bool ok = hw < HW;
    int hwc = ok ? hw : (HW - 1);

    // pass 1: sum of squares
    float ss = 0.f;
#pragma unroll 16
    for (int c = p * 160; c < (p + 1) * 160; ++c) {
        float v = src[(size_t)c * HW + hwc];
        ss += v * v;
    }
    part[p][hl] = ss;
    __syncthreads();
    if (t < 64) {
        float tot = part[0][t] + part[1][t] + part[2][t] + part[3][t];
        bool okr = (h0 * 64 + t) < HW;
        inv[t] = okr ? rsqrtf(tot) : 0.f;    // pad rows -> zeros
    }
    __syncthreads();

    // pass 2: L2-hot re-read, scale, single-rounded bf16 stash
    float iv = inv[hl];
#pragma unroll 8
    for (int c = p * 160; c < (p + 1) * 160; ++c) {
        float v = src[(size_t)c * HW + hwc] * iv;
        tile[c][hl] = __float2bfloat16(v);   // lanes consecutive: conflict-free
    }
    __syncthreads();

    // pass 3: pack + fragment-major coalesced stores (20 x 1KiB per wave-group)
    int rl  = t >> 2;                // local row 0..63
    int k8  = (t & 3) * 8;
    int rb  = h0 * 4 + (rl >> 4);
    int r16 = rl & 15;
    for (int kt = 0; kt < NKT; ++kt) {
        short8 v;
#pragma unroll
        for (int j = 0; j < 8; ++j) {
            __hip_bfloat16 h = tile[kt * 32 + k8 + j][rl];
            v[j] = *(short*)&h;
        }
        *(short8*)(dst + ((size_t)rb * NKT + kt) * CHUNK + r16 * 32 + k8) = v;
    }
}

// ------------- gemm + fused top-3: m97-style glds staging -------------
__global__ __launch_bounds__(256, 2)
void gemm_top3_kernel(const __hip_bfloat16* __restrict__ qn2,
                      const __hip_bfloat16* __restrict__ sn2,
                      float* __restrict__ out) {
    __shared__ __hip_bfloat16 sbuf[64 * CHUNK];   // 64 KiB: 56 A + 8 B chunks
    __shared__ float mrg[4][64][3];

    // XCD-grouping swizzle: all 35 (n,mt) blocks of image b on one XCD
    int id  = blockIdx.x;
    int xcd = id & 7;
    int j8  = id >> 3;
    int b   = (j8 / 35) * 8 + xcd;
    if (b >= B_IMGS) return;
    int inner = j8 % 35;
    int n  = inner / 7;
    int mt = inner % 7;

    int tid  = threadIdx.x;
    int w    = tid >> 6;
    int lane = tid & 63;
    int c16  = lane & 15;
    int quad = lane >> 4;
    int frag = c16 * 32 + quad * 8;     // within-chunk fragment offset (elems)

    const __hip_bfloat16* qA = qn2 + (size_t)b * NRB * NKT * CHUNK;
    const __hip_bfloat16* qB = sn2 + ((size_t)n * NRB + mt * 4) * NKT * CHUNK;

    float4v acc[7][4];
#pragma unroll
    for (int r = 0; r < 7; ++r)
#pragma unroll
        for (int j = 0; j < 4; ++j)
            acc[r][j] = (float4v){0.f, 0.f, 0.f, 0.f};

    for (int s = 0; s < 10; ++s) {
        __syncthreads();                 // prior slab's ds_reads complete
        // stage 64 chunks; wave w moves chunks [w*16, w*16+16)
#pragma unroll
        for (int i = 0; i < 16; ++i) {
            int cid = w * 16 + i;
            const __hip_bfloat16* g;
            if (cid < 56) {
                int rb = cid >> 1;
                g = qA + ((size_t)rb * NKT + 2 * s + (cid & 1)) * CHUNK;
            } else {
                int jb = (cid - 56) >> 1;
                g = qB + ((size_t)jb * NKT + 2 * s + (cid & 1)) * CHUNK;
            }
            glds16(g + lane * 8, sbuf + cid * CHUNK + lane * 8);
        }
        __syncthreads();                 // vmcnt(0)+barrier: staging visible

#pragma unroll
        for (int kk = 0; kk < 2; ++kk) {
            short8 a[7], bfr[4];
#pragma unroll
            for (int r = 0; r < 7; ++r)
                a[r] = *(const short8*)(sbuf + ((r * 4 + w) * 2 + kk) * CHUNK + frag);
#pragma unroll
            for (int j = 0; j < 4; ++j)
                bfr[j] = *(const short8*)(sbuf + (56 + j * 2 + kk) * CHUNK + frag);
#pragma unroll
            for (int r = 0; r < 7; ++r)
#pragma unroll
                for (int j = 0; j < 4; ++j)
                    acc[r][j] = __builtin_amdgcn_mfma_f32_16x16x32_bf16(
                        a[r], bfr[j], acc[r][j], 0, 0, 0);
        }
    }

    // ---- in-register top-3 over this wave's 112 rows, per owned column ----
    float T0[4], T1[4], T2[4];
#pragma unroll
    for (int j = 0; j < 4; ++j) { T0[j] = -1e30f; T1[j] = -1e30f; T2[j] = -1e30f; }
#pragma unroll
    for (int r = 0; r < 7; ++r)
#pragma unroll
        for (int j = 0; j < 4; ++j)
#pragma unroll
            for (int g = 0; g < 4; ++g) {
                int row = r * 64 + w * 16 + quad * 4 + g;   // C layout: row=quad*4+reg
                float v = (row < HW) ? acc[r][j][g] : -1e30f;
                ins3(T0[j], T1[j], T2[j], v);
            }

    // quad-butterfly merge (rows spread over lane bits 4,5)
#pragma unroll
    for (int j = 0; j < 4; ++j) {
#pragma unroll
        for (int d = 16; d <= 32; d <<= 1) {
            float o0 = __shfl_xor(T0[j], d, 64);
            float o1 = __shfl_xor(T1[j], d, 64);
            float o2 = __shfl_xor(T2[j], d, 64);
            ins3(T0[j], T1[j], T2[j], o0);
            ins3(T0[j], T1[j], T2[j], o1);
            ins3(T0[j], T1[j], T2[j], o2);
        }
    }

    // cross-wave merge via LDS
    if (quad == 0) {
#pragma unroll
        for (int j = 0; j < 4; ++j) {
            mrg[w][j * 16 + c16][0] = T0[j];
            mrg[w][j * 16 + c16][1] = T1[j];
            mrg[w][j * 16 + c16][2] = T2[j];
        }
    }
    __syncthreads();
    if (tid < 64) {
        int col = tid;
        float t0 = mrg[0][col][0], t1 = mrg[0][col][1], t2 = mrg[0][col][2];
#pragma unroll
        for (int ww = 1; ww < 4; ++ww) {
            ins3(t0, t1, t2, mrg[ww][col][0]);
            ins3(t0, t1, t2, mrg[ww][col][1]);
            ins3(t0, t1, t2, mrg[ww][col][2]);
        }
        float s = (mt * 64 + col < HW) ? (t0 + t1 + t2) : 0.f;
#pragma unroll
        for (int d = 32; d >= 1; d >>= 1) s += __shfl_xor(s, d, 64);
        if (tid == 0) atomicAdd(&out[b * N_CLS + n], s);
    }
}

extern "C" void kernel_launch(void* const* d_in, const int* in_sizes, int n_in,
                              void* d_out, int out_size, void* d_ws, size_t ws_size,
                              hipStream_t stream) {
    const float* q = (const float*)d_in[0];
    const float* S = (const float*)d_in[1];
    float* out = (float*)d_out;

    char* ws = (char*)d_ws;
    size_t off = 0;
    __hip_bfloat16* qn2 = (__hip_bfloat16*)(ws + off);
    off += (size_t)B_IMGS * NRB * NKT * CHUNK * 2;  off = (off + 255) & ~(size_t)255;
    __hip_bfloat16* sn2 = (__hip_bfloat16*)(ws + off);

    hipMemsetAsync(d_out, 0, (size_t)out_size * sizeof(float), stream);

    prep_kernel<<<dim3(80 * 7), dim3(256), 0, stream>>>(q, S, qn2, sn2);
    // 8 XCD groups x 350 slots; dead blocks (b>=75) exit immediately
    gemm_top3_kernel<<<dim3(8 * 350), dim3(256), 0, stream>>>(qn2, sn2, out);
}